// Round 1
// baseline (182.456 us; speedup 1.0000x reference)
//
#include <hip/hip_runtime.h>
#include <hip/hip_bf16.h>
#include <cstdint>

#define IN_DIM 256
#define OUT_DIM 128
#define MAXK 512   // max edges per target row; Poisson(64) -> P(>512) ~ 0

// ---------------- GEMM: h = features @ W  (fp32, tiled) ----------------
// BM=64 rows, BN=128 (all cols), BK=32. 256 threads, each computes 8x4.
__global__ __launch_bounds__(256) void gemm_h(const float* __restrict__ A,
                                              const float* __restrict__ Wm,
                                              float* __restrict__ H, int N) {
    __shared__ float As[32][64];    // [k][m]
    __shared__ float Bs[32][128];   // [k][n]
    const int bm  = blockIdx.x * 64;
    const int tid = threadIdx.x;
    const int tx  = tid & 31;   // cols tx*4 .. tx*4+3
    const int ty  = tid >> 5;   // rows ty*8 .. ty*8+7
    float acc[8][4] = {};
    for (int k0 = 0; k0 < IN_DIM; k0 += 32) {
        // A tile: 64x32, transposed into As[k][m]
        {
            const int r  = tid >> 3;          // 0..31
            const int c4 = (tid & 7) * 4;     // 0..28
            #pragma unroll
            for (int p = 0; p < 2; ++p) {
                const int row = bm + r + p * 32;
                float4 v = make_float4(0.f, 0.f, 0.f, 0.f);
                if (row < N) v = *(const float4*)(A + (size_t)row * IN_DIM + k0 + c4);
                As[c4 + 0][r + p * 32] = v.x;
                As[c4 + 1][r + p * 32] = v.y;
                As[c4 + 2][r + p * 32] = v.z;
                As[c4 + 3][r + p * 32] = v.w;
            }
        }
        // B tile: 32x128
        {
            const int r  = tid >> 5;          // 0..7
            const int c4 = (tid & 31) * 4;    // 0..124
            #pragma unroll
            for (int p = 0; p < 4; ++p) {
                const int row = r + p * 8;
                float4 v = *(const float4*)(Wm + (size_t)(k0 + row) * OUT_DIM + c4);
                *(float4*)&Bs[row][c4] = v;
            }
        }
        __syncthreads();
        #pragma unroll
        for (int k = 0; k < 32; ++k) {
            float a[8], b[4];
            *(float4*)&a[0] = *(const float4*)&As[k][ty * 8];
            *(float4*)&a[4] = *(const float4*)&As[k][ty * 8 + 4];
            *(float4*)&b[0] = *(const float4*)&Bs[k][tx * 4];
            #pragma unroll
            for (int i = 0; i < 8; ++i)
                #pragma unroll
                for (int j = 0; j < 4; ++j)
                    acc[i][j] = fmaf(a[i], b[j], acc[i][j]);
        }
        __syncthreads();
    }
    #pragma unroll
    for (int i = 0; i < 8; ++i) {
        const int row = bm + ty * 8 + i;
        if (row < N) {
            float4 v = make_float4(acc[i][0], acc[i][1], acc[i][2], acc[i][3]);
            *(float4*)(H + (size_t)row * OUT_DIM + tx * 4) = v;
        }
    }
}

// ---------------- per-node scores s1 = h.a1, s2 = h.a2 ----------------
__global__ __launch_bounds__(256) void score_kernel(const float* __restrict__ H,
                                                    const float* __restrict__ av,
                                                    float* __restrict__ s1,
                                                    float* __restrict__ s2, int N) {
    const int wave = threadIdx.x >> 6;
    const int lane = threadIdx.x & 63;
    const int n = blockIdx.x * 4 + wave;
    if (n >= N) return;
    const float h0 = H[(size_t)n * OUT_DIM + lane];
    const float h1 = H[(size_t)n * OUT_DIM + 64 + lane];
    float p1 = h0 * av[lane]       + h1 * av[64 + lane];
    float p2 = h0 * av[128 + lane] + h1 * av[192 + lane];
    #pragma unroll
    for (int o = 32; o; o >>= 1) {
        p1 += __shfl_xor(p1, o);
        p2 += __shfl_xor(p2, o);
    }
    if (lane == 0) { s1[n] = p1; s2[n] = p2; }
}

// ---------------- CSR build ----------------
__global__ __launch_bounds__(256) void count_kernel(const int* __restrict__ tio,
                                                    int* __restrict__ counts, int E) {
    const int k = blockIdx.x * 256 + threadIdx.x;
    if (k < E) atomicAdd(&counts[tio[k]], 1);
}

// single block, 1024 threads, T <= 4096
__global__ __launch_bounds__(1024) void scan_kernel(const int* __restrict__ counts,
                                                    int* __restrict__ offsets,
                                                    int* __restrict__ cursor, int T) {
    __shared__ int sh[1024];
    const int t = threadIdx.x;
    const int base = t * 4;
    int c0 = (base + 0 < T) ? counts[base + 0] : 0;
    int c1 = (base + 1 < T) ? counts[base + 1] : 0;
    int c2 = (base + 2 < T) ? counts[base + 2] : 0;
    int c3 = (base + 3 < T) ? counts[base + 3] : 0;
    const int s = c0 + c1 + c2 + c3;
    sh[t] = s;
    __syncthreads();
    for (int off = 1; off < 1024; off <<= 1) {
        int v = 0;
        if (t >= off) v = sh[t - off];
        __syncthreads();
        if (t >= off) sh[t] += v;
        __syncthreads();
    }
    const int excl = sh[t] - s;
    int o0 = excl, o1 = excl + c0, o2 = excl + c0 + c1, o3 = excl + c0 + c1 + c2;
    if (base + 0 < T) { offsets[base + 0] = o0; cursor[base + 0] = o0; }
    if (base + 1 < T) { offsets[base + 1] = o1; cursor[base + 1] = o1; }
    if (base + 2 < T) { offsets[base + 2] = o2; cursor[base + 2] = o2; }
    if (base + 3 < T) { offsets[base + 3] = o3; cursor[base + 3] = o3; }
    if (t == 1023) offsets[T] = sh[1023];
}

__global__ __launch_bounds__(256) void scatter_kernel(const int* __restrict__ tio,
                                                      int* __restrict__ cursor,
                                                      int* __restrict__ edge_list, int E) {
    const int k = blockIdx.x * 256 + threadIdx.x;
    if (k < E) {
        const int t = tio[k];
        const int pos = atomicAdd(&cursor[t], 1);
        edge_list[pos] = k;
    }
}

// ---------------- per-row: dedup + softmax + gather-aggregate + ELU ----------------
__global__ __launch_bounds__(64) void row_kernel(const int* __restrict__ offsets,
                                                 const int* __restrict__ edge_list,
                                                 const int* __restrict__ adj,
                                                 const float* __restrict__ s1,
                                                 const float* __restrict__ s2,
                                                 const float* __restrict__ H,
                                                 float* __restrict__ out,
                                                 int E, int Nn) {
    __shared__ int   sh_dst[MAXK];
    __shared__ int   sh_kk[MAXK];
    __shared__ float sh_p[MAXK];
    __shared__ int   sh_act[MAXK];
    const int row  = blockIdx.x;
    const int lane = threadIdx.x;
    const int k0 = offsets[row];
    const int k1 = offsets[row + 1];
    int cnt = k1 - k0;
    if (cnt > MAXK) cnt = MAXK;   // statistically unreachable safety clamp

    for (int i = lane; i < cnt; i += 64) {
        const int kk  = edge_list[k0 + i];
        const int src = adj[kk];
        const int dst = adj[E + kk];
        float ev = s1[src] + s2[dst];
        ev = ev > 0.f ? ev : 0.2f * ev;      // leaky_relu(0.2)
        sh_dst[i] = dst; sh_kk[i] = kk; sh_p[i] = ev;
    }
    __syncthreads();

    // dedup (last write wins == max edge index) + row max over active edges
    float lm = -3.0e38f;
    for (int i = lane; i < cnt; i += 64) {
        const int dst = sh_dst[i];
        const int kk  = sh_kk[i];
        bool act = true;
        for (int j = 0; j < cnt; ++j)
            if (sh_dst[j] == dst && sh_kk[j] > kk) { act = false; break; }
        sh_act[i] = act ? 1 : 0;
        if (act) lm = fmaxf(lm, sh_p[i]);
    }
    #pragma unroll
    for (int o = 32; o; o >>= 1) lm = fmaxf(lm, __shfl_xor(lm, o));
    __syncthreads();

    float ls = 0.f;
    for (int i = lane; i < cnt; i += 64) {
        const float p = sh_act[i] ? expf(sh_p[i] - lm) : 0.f;
        sh_p[i] = p;
        ls += p;
    }
    #pragma unroll
    for (int o = 32; o; o >>= 1) ls += __shfl_xor(ls, o);
    __syncthreads();
    const float inv = (cnt > 0 && ls > 0.f) ? 1.f / ls : 0.f;

    // h_prime[row] = sum_i p_i * h[dst_i]; each lane owns 2 output dims
    float2 acc = make_float2(0.f, 0.f);
    for (int j = 0; j < cnt; ++j) {
        const float p = sh_p[j];
        if (p != 0.f) {
            const int dst = sh_dst[j];
            const float2 hv = *(const float2*)(H + (size_t)dst * OUT_DIM + lane * 2);
            acc.x = fmaf(p, hv.x, acc.x);
            acc.y = fmaf(p, hv.y, acc.y);
        }
    }
    acc.x *= inv; acc.y *= inv;

    if (cnt == 0) {   // empty row: softmax over all -9e15 -> uniform 1/Nn
        float2 a2 = make_float2(0.f, 0.f);
        for (int n = 0; n < Nn; ++n) {
            const float2 hv = *(const float2*)(H + (size_t)n * OUT_DIM + lane * 2);
            a2.x += hv.x; a2.y += hv.y;
        }
        acc.x = a2.x / (float)Nn; acc.y = a2.y / (float)Nn;
    }

    // ELU
    acc.x = acc.x > 0.f ? acc.x : expm1f(acc.x);
    acc.y = acc.y > 0.f ? acc.y : expm1f(acc.y);
    *(float2*)(out + (size_t)row * OUT_DIM + lane * 2) = acc;
}

extern "C" void kernel_launch(void* const* d_in, const int* in_sizes, int n_in,
                              void* d_out, int out_size, void* d_ws, size_t ws_size,
                              hipStream_t stream) {
    const float* features = (const float*)d_in[0];
    const int*   adj      = (const int*)d_in[1];   // [2, E]
    const int*   tio      = (const int*)d_in[2];   // [E]
    const float* Wm       = (const float*)d_in[3]; // [256,128]
    const float* av       = (const float*)d_in[4]; // [256]
    float* out = (float*)d_out;

    const int N = in_sizes[0] / IN_DIM;
    const int E = in_sizes[2];
    const int T = out_size / OUT_DIM;

    char* ws = (char*)d_ws;
    float* h  = (float*)ws;            ws += (size_t)N * OUT_DIM * 4;
    float* s1 = (float*)ws;            ws += (size_t)N * 4;
    float* s2 = (float*)ws;            ws += (size_t)N * 4;
    int* counts    = (int*)ws;         ws += (size_t)(T + 1) * 4;
    int* offsets   = (int*)ws;         ws += (size_t)(T + 1) * 4;
    int* cursor    = (int*)ws;         ws += (size_t)T * 4;
    int* edge_list = (int*)ws;         ws += (size_t)E * 4;

    hipMemsetAsync(counts, 0, (size_t)T * 4, stream);
    gemm_h<<<(N + 63) / 64, 256, 0, stream>>>(features, Wm, h, N);
    score_kernel<<<(N + 3) / 4, 256, 0, stream>>>(h, av, s1, s2, N);
    count_kernel<<<(E + 255) / 256, 256, 0, stream>>>(tio, counts, E);
    scan_kernel<<<1, 1024, 0, stream>>>(counts, offsets, cursor, T);
    scatter_kernel<<<(E + 255) / 256, 256, 0, stream>>>(tio, cursor, edge_list, E);
    row_kernel<<<T, 64, 0, stream>>>(offsets, edge_list, adj, s1, s2, h, out, E, N);
}

// Round 2
// 136.788 us; speedup vs baseline: 1.3339x; 1.3339x over previous
//
#include <hip/hip_runtime.h>
#include <hip/hip_bf16.h>
#include <cstdint>

#define IN_DIM 256
#define OUT_DIM 128
#define MAXK 512   // max edges per target row; Poisson(64) -> P(>512) ~ 0

typedef __attribute__((ext_vector_type(8))) short short8;
typedef __attribute__((ext_vector_type(4))) float f32x4;

__device__ __forceinline__ unsigned short f2bf(float f) {
    __hip_bfloat16 b = __float2bfloat16(f);
    return *reinterpret_cast<unsigned short*>(&b);
}

// ---------------- one-time: Wt[n][k] = bf16(W[k][n]) ----------------
__global__ __launch_bounds__(256) void wt_kernel(const float* __restrict__ Wm,
                                                 unsigned short* __restrict__ Wt) {
    const int idx = blockIdx.x * 256 + threadIdx.x;   // 256*128 = 32768
    const int k = idx >> 7;
    const int n = idx & 127;
    Wt[n * 256 + k] = f2bf(Wm[idx]);
}

// ---------------- GEMM: h = features @ W via bf16 MFMA ----------------
// BM=64, BN=128 (full), BK=128 x 2 chunks. 256 threads = 4 waves (2x2),
// each wave computes 32x64 = 2x4 fragments of 16x16x32.
__global__ __launch_bounds__(256) void gemm_h(const float* __restrict__ A,
                                              const unsigned short* __restrict__ Wt,
                                              float* __restrict__ H, int Nn) {
    __shared__ unsigned short Abuf[64 * 128];    // [m][k] bf16, XOR-swizzled
    __shared__ unsigned short Bbuf[128 * 128];   // [n][k] bf16, XOR-swizzled
    char* Ab = (char*)Abuf;
    char* Bb = (char*)Bbuf;
    const int tid  = threadIdx.x;
    const int lane = tid & 63;
    const int wave = tid >> 6;
    const int wm = wave >> 1, wn = wave & 1;
    const int bm = blockIdx.x * 64;
    const int l15 = lane & 15;
    const int lhi = lane >> 4;

    f32x4 acc[2][4];
    #pragma unroll
    for (int i = 0; i < 2; ++i)
        #pragma unroll
        for (int j = 0; j < 4; ++j) acc[i][j] = (f32x4){0.f, 0.f, 0.f, 0.f};

    for (int c = 0; c < 2; ++c) {
        const int k0 = c * 128;
        // stage A tile 64x128 fp32 -> bf16 (convert in flight)
        #pragma unroll
        for (int i = 0; i < 8; ++i) {
            const int idx = tid + 256 * i;
            const int row = idx >> 5;          // 0..63
            const int c4  = idx & 31;          // float4 slot (32/row)
            const int gr  = bm + row;
            float4 v = make_float4(0.f, 0.f, 0.f, 0.f);
            if (gr < Nn) v = *(const float4*)(A + (size_t)gr * IN_DIM + k0 + c4 * 4);
            const unsigned int lo = (unsigned)f2bf(v.x) | ((unsigned)f2bf(v.y) << 16);
            const unsigned int hi = (unsigned)f2bf(v.z) | ((unsigned)f2bf(v.w) << 16);
            const int byte = row * 256 + ((c4 * 8) ^ ((row & 7) << 4));
            *(uint2*)(Ab + byte) = make_uint2(lo, hi);
        }
        // stage B tile 128n x 128k from pre-transposed Wt
        #pragma unroll
        for (int i = 0; i < 8; ++i) {
            const int idx  = tid + 256 * i;
            const int n    = idx >> 4;         // 0..127
            const int slot = idx & 15;         // 16B slot (16/row)
            const uint4 v = *(const uint4*)(Wt + (size_t)n * 256 + k0 + slot * 8);
            const int byte = n * 256 + ((slot * 16) ^ ((n & 7) << 4));
            *(uint4*)(Bb + byte) = v;
        }
        __syncthreads();
        #pragma unroll
        for (int ks = 0; ks < 4; ++ks) {
            const int kb = ks * 64 + lhi * 16;   // byte offset of lane's 8 bf16
            short8 a[2], b[4];
            #pragma unroll
            for (int i = 0; i < 2; ++i) {
                const int m = wm * 32 + i * 16 + l15;
                a[i] = *(const short8*)(Ab + m * 256 + (kb ^ ((m & 7) << 4)));
            }
            #pragma unroll
            for (int j = 0; j < 4; ++j) {
                const int n = wn * 64 + j * 16 + l15;
                b[j] = *(const short8*)(Bb + n * 256 + (kb ^ ((n & 7) << 4)));
            }
            #pragma unroll
            for (int i = 0; i < 2; ++i)
                #pragma unroll
                for (int j = 0; j < 4; ++j)
                    acc[i][j] = __builtin_amdgcn_mfma_f32_16x16x32_bf16(a[i], b[j], acc[i][j], 0, 0, 0);
        }
        __syncthreads();
    }
    // epilogue: D row = (lane>>4)*4 + r, col = lane&15 (within 16x16 frag)
    #pragma unroll
    for (int i = 0; i < 2; ++i) {
        #pragma unroll
        for (int r = 0; r < 4; ++r) {
            const int row = bm + wm * 32 + i * 16 + lhi * 4 + r;
            if (row < Nn) {
                #pragma unroll
                for (int j = 0; j < 4; ++j) {
                    const int col = wn * 64 + j * 16 + l15;
                    H[(size_t)row * OUT_DIM + col] = acc[i][j][r];
                }
            }
        }
    }
}

// ---------------- per-node scores s1 = h.a1, s2 = h.a2 ----------------
__global__ __launch_bounds__(256) void score_kernel(const float* __restrict__ H,
                                                    const float* __restrict__ av,
                                                    float* __restrict__ s1,
                                                    float* __restrict__ s2, int N) {
    const int wave = threadIdx.x >> 6;
    const int lane = threadIdx.x & 63;
    const int n = blockIdx.x * 4 + wave;
    if (n >= N) return;
    const float h0 = H[(size_t)n * OUT_DIM + lane];
    const float h1 = H[(size_t)n * OUT_DIM + 64 + lane];
    float p1 = h0 * av[lane]       + h1 * av[64 + lane];
    float p2 = h0 * av[128 + lane] + h1 * av[192 + lane];
    #pragma unroll
    for (int o = 32; o; o >>= 1) {
        p1 += __shfl_xor(p1, o);
        p2 += __shfl_xor(p2, o);
    }
    if (lane == 0) { s1[n] = p1; s2[n] = p2; }
}

// ---------------- CSR build ----------------
__global__ __launch_bounds__(256) void count_kernel(const int* __restrict__ tio,
                                                    int* __restrict__ counts, int E) {
    const int k = blockIdx.x * 256 + threadIdx.x;
    if (k < E) atomicAdd(&counts[tio[k]], 1);
}

__global__ __launch_bounds__(1024) void scan_kernel(const int* __restrict__ counts,
                                                    int* __restrict__ offsets,
                                                    int* __restrict__ cursor, int T) {
    __shared__ int sh[1024];
    const int t = threadIdx.x;
    const int base = t * 4;
    int c0 = (base + 0 < T) ? counts[base + 0] : 0;
    int c1 = (base + 1 < T) ? counts[base + 1] : 0;
    int c2 = (base + 2 < T) ? counts[base + 2] : 0;
    int c3 = (base + 3 < T) ? counts[base + 3] : 0;
    const int s = c0 + c1 + c2 + c3;
    sh[t] = s;
    __syncthreads();
    for (int off = 1; off < 1024; off <<= 1) {
        int v = 0;
        if (t >= off) v = sh[t - off];
        __syncthreads();
        if (t >= off) sh[t] += v;
        __syncthreads();
    }
    const int excl = sh[t] - s;
    int o0 = excl, o1 = excl + c0, o2 = excl + c0 + c1, o3 = excl + c0 + c1 + c2;
    if (base + 0 < T) { offsets[base + 0] = o0; cursor[base + 0] = o0; }
    if (base + 1 < T) { offsets[base + 1] = o1; cursor[base + 1] = o1; }
    if (base + 2 < T) { offsets[base + 2] = o2; cursor[base + 2] = o2; }
    if (base + 3 < T) { offsets[base + 3] = o3; cursor[base + 3] = o3; }
    if (t == 1023) offsets[T] = sh[1023];
}

__global__ __launch_bounds__(256) void scatter_kernel(const int* __restrict__ tio,
                                                      int* __restrict__ cursor,
                                                      int* __restrict__ edge_list, int E) {
    const int k = blockIdx.x * 256 + threadIdx.x;
    if (k < E) {
        const int t = tio[k];
        const int pos = atomicAdd(&cursor[t], 1);
        edge_list[pos] = k;
    }
}

// ---------------- per-row: dedup + softmax + gather-aggregate + ELU ----------------
// 256 threads: 4 waves split the edge gathers, LDS partial-sum reduce.
__global__ __launch_bounds__(256) void row_kernel(const int* __restrict__ offsets,
                                                  const int* __restrict__ edge_list,
                                                  const int* __restrict__ adj,
                                                  const float* __restrict__ s1,
                                                  const float* __restrict__ s2,
                                                  const float* __restrict__ H,
                                                  float* __restrict__ out,
                                                  int E, int Nn) {
    __shared__ int   sh_dst[MAXK];
    __shared__ int   sh_kk[MAXK];
    __shared__ float sh_p[MAXK];
    __shared__ unsigned char sh_act[MAXK];
    __shared__ float psum[4][128];
    __shared__ float red[4];
    const int row  = blockIdx.x;
    const int tid  = threadIdx.x;
    const int lane = tid & 63;
    const int wave = tid >> 6;
    const int k0 = offsets[row];
    const int k1 = offsets[row + 1];
    int cnt = k1 - k0;
    if (cnt > MAXK) cnt = MAXK;

    for (int i = tid; i < cnt; i += 256) {
        const int kk  = edge_list[k0 + i];
        const int src = adj[kk];
        const int dst = adj[E + kk];
        float ev = s1[src] + s2[dst];
        ev = ev > 0.f ? ev : 0.2f * ev;      // leaky_relu(0.2)
        sh_dst[i] = dst; sh_kk[i] = kk; sh_p[i] = ev;
    }
    __syncthreads();

    // dedup (last write wins == max edge index) + row max over active edges
    float lm = -3.0e38f;
    for (int i = tid; i < cnt; i += 256) {
        const int dst = sh_dst[i];
        const int kk  = sh_kk[i];
        bool act = true;
        for (int j = 0; j < cnt; ++j)
            if (sh_dst[j] == dst && sh_kk[j] > kk) { act = false; break; }
        sh_act[i] = act ? 1 : 0;
        if (act) lm = fmaxf(lm, sh_p[i]);
    }
    #pragma unroll
    for (int o = 32; o; o >>= 1) lm = fmaxf(lm, __shfl_xor(lm, o));
    if (lane == 0) red[wave] = lm;
    __syncthreads();
    lm = fmaxf(fmaxf(red[0], red[1]), fmaxf(red[2], red[3]));

    float ls = 0.f;
    for (int i = tid; i < cnt; i += 256) {
        const float p = sh_act[i] ? __expf(sh_p[i] - lm) : 0.f;
        sh_p[i] = p;
        ls += p;
    }
    #pragma unroll
    for (int o = 32; o; o >>= 1) ls += __shfl_xor(ls, o);
    __syncthreads();                       // red[] reads done before overwrite
    if (lane == 0) red[wave] = ls;
    __syncthreads();
    ls = red[0] + red[1] + red[2] + red[3];
    const float inv = (cnt > 0 && ls > 0.f) ? 1.f / ls : 0.f;

    // waves split the edges; each lane owns 2 output dims
    float2 acc = make_float2(0.f, 0.f);
    for (int j = wave; j < cnt; j += 4) {
        const float p = sh_p[j];
        if (p != 0.f) {
            const int dst = sh_dst[j];
            const float2 hv = *(const float2*)(H + (size_t)dst * OUT_DIM + lane * 2);
            acc.x = fmaf(p, hv.x, acc.x);
            acc.y = fmaf(p, hv.y, acc.y);
        }
    }
    psum[wave][lane * 2 + 0] = acc.x;
    psum[wave][lane * 2 + 1] = acc.y;
    __syncthreads();

    if (tid < 128) {
        float s = (psum[0][tid] + psum[1][tid] + psum[2][tid] + psum[3][tid]) * inv;
        if (cnt == 0) {   // empty row: softmax over all -9e15 -> uniform 1/Nn
            float t = 0.f;
            for (int n = 0; n < Nn; ++n) t += H[(size_t)n * OUT_DIM + tid];
            s = t / (float)Nn;
        }
        s = s > 0.f ? s : expm1f(s);       // ELU
        out[(size_t)row * OUT_DIM + tid] = s;
    }
}

extern "C" void kernel_launch(void* const* d_in, const int* in_sizes, int n_in,
                              void* d_out, int out_size, void* d_ws, size_t ws_size,
                              hipStream_t stream) {
    const float* features = (const float*)d_in[0];
    const int*   adj      = (const int*)d_in[1];   // [2, E]
    const int*   tio      = (const int*)d_in[2];   // [E]
    const float* Wm       = (const float*)d_in[3]; // [256,128]
    const float* av       = (const float*)d_in[4]; // [256]
    float* out = (float*)d_out;

    const int N = in_sizes[0] / IN_DIM;
    const int E = in_sizes[2];
    const int T = out_size / OUT_DIM;

    char* ws = (char*)d_ws;
    float* h  = (float*)ws;                 ws += (size_t)N * OUT_DIM * 4;
    unsigned short* Wt = (unsigned short*)ws; ws += (size_t)IN_DIM * OUT_DIM * 2;
    float* s1 = (float*)ws;                 ws += (size_t)N * 4;
    float* s2 = (float*)ws;                 ws += (size_t)N * 4;
    int* counts    = (int*)ws;              ws += (size_t)(T + 1) * 4;
    int* offsets   = (int*)ws;              ws += (size_t)(T + 1) * 4;
    int* cursor    = (int*)ws;              ws += (size_t)T * 4;
    int* edge_list = (int*)ws;              ws += (size_t)E * 4;

    hipMemsetAsync(counts, 0, (size_t)T * 4, stream);
    wt_kernel<<<(IN_DIM * OUT_DIM) / 256, 256, 0, stream>>>(Wm, Wt);
    gemm_h<<<(N + 63) / 64, 256, 0, stream>>>(features, Wt, h, N);
    score_kernel<<<(N + 3) / 4, 256, 0, stream>>>(h, av, s1, s2, N);
    count_kernel<<<(E + 255) / 256, 256, 0, stream>>>(tio, counts, E);
    scan_kernel<<<1, 1024, 0, stream>>>(counts, offsets, cursor, T);
    scatter_kernel<<<(E + 255) / 256, 256, 0, stream>>>(tio, cursor, edge_list, E);
    row_kernel<<<T, 256, 0, stream>>>(offsets, edge_list, adj, s1, s2, h, out, E, N);
}

// Round 3
// 104.719 us; speedup vs baseline: 1.7423x; 1.3062x over previous
//
#include <hip/hip_runtime.h>
#include <hip/hip_bf16.h>
#include <cstdint>

#define IN_DIM 256
#define OUT_DIM 128
#define CAP 192   // max edges per target row; Poisson(64) -> P(>192) ~ e^-40

typedef __attribute__((ext_vector_type(8))) short short8;
typedef __attribute__((ext_vector_type(4))) float f32x4;

__device__ __forceinline__ unsigned short f2bf(float f) {
    __hip_bfloat16 b = __float2bfloat16(f);
    return *reinterpret_cast<unsigned short*>(&b);
}
__device__ __forceinline__ float bf2f(unsigned short u) {
    union { unsigned int i; float f; } v;
    v.i = ((unsigned int)u) << 16;
    return v.f;
}

// ---------------- one-time: Wt[n][k] = bf16(W[k][n]) ----------------
__global__ __launch_bounds__(256) void wt_kernel(const float* __restrict__ Wm,
                                                 unsigned short* __restrict__ Wt) {
    const int idx = blockIdx.x * 256 + threadIdx.x;   // 256*128 = 32768
    const int k = idx >> 7;
    const int n = idx & 127;
    Wt[n * 256 + k] = f2bf(Wm[idx]);
}

// ---------------- GEMM: Hb = bf16(features @ W) via bf16 MFMA ----------------
// BM=64, BN=128 (full), BK=128 x 2 chunks. 256 threads = 4 waves (2x2).
__global__ __launch_bounds__(256) void gemm_h(const float* __restrict__ A,
                                              const unsigned short* __restrict__ Wt,
                                              unsigned short* __restrict__ Hb, int Nn) {
    __shared__ unsigned short Abuf[64 * 128];    // [m][k] bf16, XOR-swizzled
    __shared__ unsigned short Bbuf[128 * 128];   // [n][k] bf16, XOR-swizzled
    char* Ab = (char*)Abuf;
    char* Bb = (char*)Bbuf;
    const int tid  = threadIdx.x;
    const int lane = tid & 63;
    const int wave = tid >> 6;
    const int wm = wave >> 1, wn = wave & 1;
    const int bm = blockIdx.x * 64;
    const int l15 = lane & 15;
    const int lhi = lane >> 4;

    f32x4 acc[2][4];
    #pragma unroll
    for (int i = 0; i < 2; ++i)
        #pragma unroll
        for (int j = 0; j < 4; ++j) acc[i][j] = (f32x4){0.f, 0.f, 0.f, 0.f};

    for (int c = 0; c < 2; ++c) {
        const int k0 = c * 128;
        // stage A tile 64x128 fp32 -> bf16 (convert in flight)
        #pragma unroll
        for (int i = 0; i < 8; ++i) {
            const int idx = tid + 256 * i;
            const int row = idx >> 5;          // 0..63
            const int c4  = idx & 31;          // float4 slot (32/row)
            const int gr  = bm + row;
            float4 v = make_float4(0.f, 0.f, 0.f, 0.f);
            if (gr < Nn) v = *(const float4*)(A + (size_t)gr * IN_DIM + k0 + c4 * 4);
            const unsigned int lo = (unsigned)f2bf(v.x) | ((unsigned)f2bf(v.y) << 16);
            const unsigned int hi = (unsigned)f2bf(v.z) | ((unsigned)f2bf(v.w) << 16);
            const int byte = row * 256 + ((c4 * 8) ^ ((row & 7) << 4));
            *(uint2*)(Ab + byte) = make_uint2(lo, hi);
        }
        // stage B tile 128n x 128k from pre-transposed Wt
        #pragma unroll
        for (int i = 0; i < 8; ++i) {
            const int idx  = tid + 256 * i;
            const int n    = idx >> 4;         // 0..127
            const int slot = idx & 15;         // 16B slot (16/row)
            const uint4 v = *(const uint4*)(Wt + (size_t)n * 256 + k0 + slot * 8);
            const int byte = n * 256 + ((slot * 16) ^ ((n & 7) << 4));
            *(uint4*)(Bb + byte) = v;
        }
        __syncthreads();
        #pragma unroll
        for (int ks = 0; ks < 4; ++ks) {
            const int kb = ks * 64 + lhi * 16;   // byte offset of lane's 8 bf16
            short8 a[2], b[4];
            #pragma unroll
            for (int i = 0; i < 2; ++i) {
                const int m = wm * 32 + i * 16 + l15;
                a[i] = *(const short8*)(Ab + m * 256 + (kb ^ ((m & 7) << 4)));
            }
            #pragma unroll
            for (int j = 0; j < 4; ++j) {
                const int n = wn * 64 + j * 16 + l15;
                b[j] = *(const short8*)(Bb + n * 256 + (kb ^ ((n & 7) << 4)));
            }
            #pragma unroll
            for (int i = 0; i < 2; ++i)
                #pragma unroll
                for (int j = 0; j < 4; ++j)
                    acc[i][j] = __builtin_amdgcn_mfma_f32_16x16x32_bf16(a[i], b[j], acc[i][j], 0, 0, 0);
        }
        __syncthreads();
    }
    // epilogue: D row = (lane>>4)*4 + r, col = lane&15 (within 16x16 frag)
    #pragma unroll
    for (int i = 0; i < 2; ++i) {
        #pragma unroll
        for (int r = 0; r < 4; ++r) {
            const int row = bm + wm * 32 + i * 16 + lhi * 4 + r;
            if (row < Nn) {
                #pragma unroll
                for (int j = 0; j < 4; ++j) {
                    const int col = wn * 64 + j * 16 + l15;
                    Hb[(size_t)row * OUT_DIM + col] = f2bf(acc[i][j][r]);
                }
            }
        }
    }
}

// ---------------- per-node scores s1 = h.a1, s2 = h.a2 (bf16 H) ----------------
__global__ __launch_bounds__(256) void score_kernel(const unsigned short* __restrict__ Hb,
                                                    const float* __restrict__ av,
                                                    float* __restrict__ s1,
                                                    float* __restrict__ s2, int N) {
    const int wave = threadIdx.x >> 6;
    const int lane = threadIdx.x & 63;
    const int n = blockIdx.x * 4 + wave;
    if (n >= N) return;
    const unsigned int v = *(const unsigned int*)(Hb + (size_t)n * OUT_DIM + lane * 2);
    const float h0 = bf2f((unsigned short)(v & 0xffff));
    const float h1 = bf2f((unsigned short)(v >> 16));
    float p1 = h0 * av[2 * lane]       + h1 * av[2 * lane + 1];
    float p2 = h0 * av[128 + 2 * lane] + h1 * av[129 + 2 * lane];
    #pragma unroll
    for (int o = 32; o; o >>= 1) {
        p1 += __shfl_xor(p1, o);
        p2 += __shfl_xor(p2, o);
    }
    if (lane == 0) { s1[n] = p1; s2[n] = p2; }
}

// ---------------- bucketed scatter with fused leaky-relu edge score ----------------
__global__ __launch_bounds__(256) void scatter_kernel(const int* __restrict__ tio,
                                                      const int* __restrict__ adj,
                                                      const float* __restrict__ s1,
                                                      const float* __restrict__ s2,
                                                      int* __restrict__ cursor,
                                                      int* __restrict__ ek,
                                                      int* __restrict__ ed,
                                                      float* __restrict__ ee, int E) {
    const int k = blockIdx.x * 256 + threadIdx.x;
    if (k >= E) return;
    const int t   = tio[k];
    const int src = adj[k];
    const int dst = adj[E + k];
    float ev = s1[src] + s2[dst];
    ev = ev > 0.f ? ev : 0.2f * ev;          // leaky_relu(0.2)
    const int pos = atomicAdd(&cursor[t], 1);
    if (pos < CAP) {
        const int b = t * CAP + pos;
        ek[b] = k; ed[b] = dst; ee[b] = ev;
    }
}

// ---------------- per-row: dedup + softmax + wide pipelined gather + ELU ----------------
// 256 threads. Gather: 16-lane groups each load a full bf16 H row as dwordx4;
// 16 edges in flight per block per unrolled step.
__global__ __launch_bounds__(256) void row_kernel(const int* __restrict__ cursor,
                                                  const int* __restrict__ ek,
                                                  const int* __restrict__ ed,
                                                  const float* __restrict__ ee,
                                                  const unsigned short* __restrict__ Hb,
                                                  float* __restrict__ out, int Nn) {
    __shared__ int   sh_dst[CAP];
    __shared__ int   sh_kk[CAP];
    __shared__ float sh_p[CAP];
    __shared__ unsigned char sh_act[CAP];
    __shared__ float psum[16][128];
    __shared__ float red[4];
    const int row  = blockIdx.x;
    const int tid  = threadIdx.x;
    const int lane = tid & 63;
    const int wave = tid >> 6;
    int cnt = cursor[row];
    if (cnt > CAP) cnt = CAP;
    const size_t base = (size_t)row * CAP;

    for (int i = tid; i < cnt; i += 256) {
        sh_kk[i]  = ek[base + i];
        sh_dst[i] = ed[base + i];
        sh_p[i]   = ee[base + i];
    }
    __syncthreads();

    // dedup (last write wins == max edge index) + row max over active edges
    float lm = -3.0e38f;
    for (int i = tid; i < cnt; i += 256) {
        const int dst = sh_dst[i];
        const int kk  = sh_kk[i];
        bool act = true;
        for (int j = 0; j < cnt; ++j)
            if (sh_dst[j] == dst && sh_kk[j] > kk) { act = false; break; }
        sh_act[i] = act ? 1 : 0;
        if (act) lm = fmaxf(lm, sh_p[i]);
    }
    #pragma unroll
    for (int o = 32; o; o >>= 1) lm = fmaxf(lm, __shfl_xor(lm, o));
    if (lane == 0) red[wave] = lm;
    __syncthreads();
    lm = fmaxf(fmaxf(red[0], red[1]), fmaxf(red[2], red[3]));

    float ls = 0.f;
    for (int i = tid; i < cnt; i += 256) {
        const float p = sh_act[i] ? __expf(sh_p[i] - lm) : 0.f;
        sh_p[i] = p;
        ls += p;
    }
    #pragma unroll
    for (int o = 32; o; o >>= 1) ls += __shfl_xor(ls, o);
    __syncthreads();                       // red[] reuse + sh_p visibility
    if (lane == 0) red[wave] = ls;
    __syncthreads();
    ls = red[0] + red[1] + red[2] + red[3];
    const float inv = (cnt > 0 && ls > 0.f) ? 1.f / ls : 0.f;

    // gather: group g (16 lanes) handles edge j; lane&15 -> dims slot*8..+7
    const int g    = lane >> 4;
    const int slot = lane & 15;
    float acc8[8];
    #pragma unroll
    for (int d = 0; d < 8; ++d) acc8[d] = 0.f;

    int j = wave * 4 + g;
    for (; j + 16 < cnt; j += 32) {        // 2x unroll: 2 loads in flight/lane
        const float p0 = sh_p[j];
        const float p1 = sh_p[j + 16];
        const int   d0 = sh_dst[j];
        const int   d1 = sh_dst[j + 16];
        const uint4 v0 = *(const uint4*)(Hb + (size_t)d0 * OUT_DIM + slot * 8);
        const uint4 v1 = *(const uint4*)(Hb + (size_t)d1 * OUT_DIM + slot * 8);
        acc8[0] = fmaf(p0, bf2f((unsigned short)(v0.x)),       acc8[0]);
        acc8[1] = fmaf(p0, bf2f((unsigned short)(v0.x >> 16)), acc8[1]);
        acc8[2] = fmaf(p0, bf2f((unsigned short)(v0.y)),       acc8[2]);
        acc8[3] = fmaf(p0, bf2f((unsigned short)(v0.y >> 16)), acc8[3]);
        acc8[4] = fmaf(p0, bf2f((unsigned short)(v0.z)),       acc8[4]);
        acc8[5] = fmaf(p0, bf2f((unsigned short)(v0.z >> 16)), acc8[5]);
        acc8[6] = fmaf(p0, bf2f((unsigned short)(v0.w)),       acc8[6]);
        acc8[7] = fmaf(p0, bf2f((unsigned short)(v0.w >> 16)), acc8[7]);
        acc8[0] = fmaf(p1, bf2f((unsigned short)(v1.x)),       acc8[0]);
        acc8[1] = fmaf(p1, bf2f((unsigned short)(v1.x >> 16)), acc8[1]);
        acc8[2] = fmaf(p1, bf2f((unsigned short)(v1.y)),       acc8[2]);
        acc8[3] = fmaf(p1, bf2f((unsigned short)(v1.y >> 16)), acc8[3]);
        acc8[4] = fmaf(p1, bf2f((unsigned short)(v1.z)),       acc8[4]);
        acc8[5] = fmaf(p1, bf2f((unsigned short)(v1.z >> 16)), acc8[5]);
        acc8[6] = fmaf(p1, bf2f((unsigned short)(v1.w)),       acc8[6]);
        acc8[7] = fmaf(p1, bf2f((unsigned short)(v1.w >> 16)), acc8[7]);
    }
    for (; j < cnt; j += 16) {
        const float p0 = sh_p[j];
        const int   d0 = sh_dst[j];
        const uint4 v0 = *(const uint4*)(Hb + (size_t)d0 * OUT_DIM + slot * 8);
        acc8[0] = fmaf(p0, bf2f((unsigned short)(v0.x)),       acc8[0]);
        acc8[1] = fmaf(p0, bf2f((unsigned short)(v0.x >> 16)), acc8[1]);
        acc8[2] = fmaf(p0, bf2f((unsigned short)(v0.y)),       acc8[2]);
        acc8[3] = fmaf(p0, bf2f((unsigned short)(v0.y >> 16)), acc8[3]);
        acc8[4] = fmaf(p0, bf2f((unsigned short)(v0.z)),       acc8[4]);
        acc8[5] = fmaf(p0, bf2f((unsigned short)(v0.z >> 16)), acc8[5]);
        acc8[6] = fmaf(p0, bf2f((unsigned short)(v0.w)),       acc8[6]);
        acc8[7] = fmaf(p0, bf2f((unsigned short)(v0.w >> 16)), acc8[7]);
    }
    const int s = wave * 4 + g;
    *(float4*)&psum[s][slot * 8]     = make_float4(acc8[0], acc8[1], acc8[2], acc8[3]);
    *(float4*)&psum[s][slot * 8 + 4] = make_float4(acc8[4], acc8[5], acc8[6], acc8[7]);
    __syncthreads();

    if (tid < 128) {
        float v = 0.f;
        #pragma unroll
        for (int k2 = 0; k2 < 16; ++k2) v += psum[k2][tid];
        v *= inv;
        if (cnt == 0) {   // empty row: softmax over all -9e15 -> uniform 1/Nn
            float t = 0.f;
            for (int n = 0; n < Nn; ++n) t += bf2f(Hb[(size_t)n * OUT_DIM + tid]);
            v = t / (float)Nn;
        }
        v = v > 0.f ? v : expm1f(v);       // ELU
        out[(size_t)row * OUT_DIM + tid] = v;
    }
}

extern "C" void kernel_launch(void* const* d_in, const int* in_sizes, int n_in,
                              void* d_out, int out_size, void* d_ws, size_t ws_size,
                              hipStream_t stream) {
    const float* features = (const float*)d_in[0];
    const int*   adj      = (const int*)d_in[1];   // [2, E]
    const int*   tio      = (const int*)d_in[2];   // [E]
    const float* Wm       = (const float*)d_in[3]; // [256,128]
    const float* av       = (const float*)d_in[4]; // [256]
    float* out = (float*)d_out;

    const int N = in_sizes[0] / IN_DIM;
    const int E = in_sizes[2];
    const int T = out_size / OUT_DIM;

    char* ws = (char*)d_ws;
    unsigned short* Hb = (unsigned short*)ws; ws += (size_t)N * OUT_DIM * 2;
    unsigned short* Wt = (unsigned short*)ws; ws += (size_t)IN_DIM * OUT_DIM * 2;
    float* s1 = (float*)ws;                   ws += (size_t)N * 4;
    float* s2 = (float*)ws;                   ws += (size_t)N * 4;
    int* cursor = (int*)ws;                   ws += (size_t)T * 4;
    int* ek = (int*)ws;                       ws += (size_t)T * CAP * 4;
    int* ed = (int*)ws;                       ws += (size_t)T * CAP * 4;
    float* ee = (float*)ws;                   ws += (size_t)T * CAP * 4;

    hipMemsetAsync(cursor, 0, (size_t)T * 4, stream);
    wt_kernel<<<(IN_DIM * OUT_DIM) / 256, 256, 0, stream>>>(Wm, Wt);
    gemm_h<<<(N + 63) / 64, 256, 0, stream>>>(features, Wt, Hb, N);
    score_kernel<<<(N + 3) / 4, 256, 0, stream>>>(Hb, av, s1, s2, N);
    scatter_kernel<<<(E + 255) / 256, 256, 0, stream>>>(tio, adj, s1, s2, cursor, ek, ed, ee, E);
    row_kernel<<<T, 256, 0, stream>>>(cursor, ek, ed, ee, Hb, out, N);
}

// Round 4
// 90.759 us; speedup vs baseline: 2.0103x; 1.1538x over previous
//
#include <hip/hip_runtime.h>
#include <hip/hip_bf16.h>
#include <cstdint>

#define IN_DIM 256
#define OUT_DIM 128
#define CAP 192   // max edges per target row; Poisson(64) -> P(>192) ~ e^-40

typedef __attribute__((ext_vector_type(8))) short short8;
typedef __attribute__((ext_vector_type(4))) float f32x4;

__device__ __forceinline__ unsigned short f2bf(float f) {
    __hip_bfloat16 b = __float2bfloat16(f);
    return *reinterpret_cast<unsigned short*>(&b);
}
__device__ __forceinline__ float bf2f(unsigned short u) {
    union { unsigned int i; float f; } v;
    v.i = ((unsigned int)u) << 16;
    return v.f;
}

// ---------------- one-time: Wt[n][k] = bf16(W[k][n]); also zero cursor ----------------
__global__ __launch_bounds__(256) void wt_kernel(const float* __restrict__ Wm,
                                                 unsigned short* __restrict__ Wt,
                                                 int* __restrict__ cursor, int T) {
    const int idx = blockIdx.x * 256 + threadIdx.x;   // 256*128 = 32768
    const int k = idx >> 7;
    const int n = idx & 127;
    Wt[n * 256 + k] = f2bf(Wm[idx]);
    if (idx < T) cursor[idx] = 0;
}

// ---------------- GEMM: Hb = bf16(features @ W), fused s1/s2 = h . a ----------------
// BM=64, BN=128 (full), BK=128 x 2 chunks. 256 threads = 4 waves (2x2).
__global__ __launch_bounds__(256) void gemm_h(const float* __restrict__ A,
                                              const unsigned short* __restrict__ Wt,
                                              const float* __restrict__ av,
                                              unsigned short* __restrict__ Hb,
                                              float* __restrict__ s1,
                                              float* __restrict__ s2, int Nn) {
    __shared__ unsigned short Abuf[64 * 128];    // [m][k] bf16, XOR-swizzled
    __shared__ unsigned short Bbuf[128 * 128];   // [n][k] bf16, XOR-swizzled
    char* Ab = (char*)Abuf;
    char* Bb = (char*)Bbuf;
    const int tid  = threadIdx.x;
    const int lane = tid & 63;
    const int wave = tid >> 6;
    const int wm = wave >> 1, wn = wave & 1;
    const int bm = blockIdx.x * 64;
    const int l15 = lane & 15;
    const int lhi = lane >> 4;

    f32x4 acc[2][4];
    #pragma unroll
    for (int i = 0; i < 2; ++i)
        #pragma unroll
        for (int j = 0; j < 4; ++j) acc[i][j] = (f32x4){0.f, 0.f, 0.f, 0.f};

    for (int c = 0; c < 2; ++c) {
        const int k0 = c * 128;
        // stage A tile 64x128 fp32 -> bf16 (convert in flight)
        #pragma unroll
        for (int i = 0; i < 8; ++i) {
            const int idx = tid + 256 * i;
            const int row = idx >> 5;          // 0..63
            const int c4  = idx & 31;          // float4 slot (32/row)
            const int gr  = bm + row;
            float4 v = make_float4(0.f, 0.f, 0.f, 0.f);
            if (gr < Nn) v = *(const float4*)(A + (size_t)gr * IN_DIM + k0 + c4 * 4);
            const unsigned int lo = (unsigned)f2bf(v.x) | ((unsigned)f2bf(v.y) << 16);
            const unsigned int hi = (unsigned)f2bf(v.z) | ((unsigned)f2bf(v.w) << 16);
            const int byte = row * 256 + ((c4 * 8) ^ ((row & 7) << 4));
            *(uint2*)(Ab + byte) = make_uint2(lo, hi);
        }
        // stage B tile 128n x 128k from pre-transposed Wt
        #pragma unroll
        for (int i = 0; i < 8; ++i) {
            const int idx  = tid + 256 * i;
            const int n    = idx >> 4;         // 0..127
            const int slot = idx & 15;         // 16B slot (16/row)
            const uint4 v = *(const uint4*)(Wt + (size_t)n * 256 + k0 + slot * 8);
            const int byte = n * 256 + ((slot * 16) ^ ((n & 7) << 4));
            *(uint4*)(Bb + byte) = v;
        }
        __syncthreads();
        #pragma unroll
        for (int ks = 0; ks < 4; ++ks) {
            const int kb = ks * 64 + lhi * 16;   // byte offset of lane's 8 bf16
            short8 a[2], b[4];
            #pragma unroll
            for (int i = 0; i < 2; ++i) {
                const int m = wm * 32 + i * 16 + l15;
                a[i] = *(const short8*)(Ab + m * 256 + (kb ^ ((m & 7) << 4)));
            }
            #pragma unroll
            for (int j = 0; j < 4; ++j) {
                const int n = wn * 64 + j * 16 + l15;
                b[j] = *(const short8*)(Bb + n * 256 + (kb ^ ((n & 7) << 4)));
            }
            #pragma unroll
            for (int i = 0; i < 2; ++i)
                #pragma unroll
                for (int j = 0; j < 4; ++j)
                    acc[i][j] = __builtin_amdgcn_mfma_f32_16x16x32_bf16(a[i], b[j], acc[i][j], 0, 0, 0);
        }
        __syncthreads();
    }

    // ---- epilogue 1: Hb store. D row = (lane>>4)*4 + r, col = lane&15 ----
    #pragma unroll
    for (int i = 0; i < 2; ++i) {
        #pragma unroll
        for (int r = 0; r < 4; ++r) {
            const int row = bm + wm * 32 + i * 16 + lhi * 4 + r;
            if (row < Nn) {
                #pragma unroll
                for (int j = 0; j < 4; ++j) {
                    const int col = wn * 64 + j * 16 + l15;
                    Hb[(size_t)row * OUT_DIM + col] = f2bf(acc[i][j][r]);
                }
            }
        }
    }

    // ---- epilogue 2: fused s1/s2 (fp32 acc).  sc layout: [s][wn][64] in Abuf ----
    float* sc = (float*)Abuf;   // 256 floats used, Abuf free after last sync
    #pragma unroll
    for (int i = 0; i < 2; ++i) {
        #pragma unroll
        for (int r = 0; r < 4; ++r) {
            float p1 = 0.f, p2 = 0.f;
            #pragma unroll
            for (int j = 0; j < 4; ++j) {
                const int col = wn * 64 + j * 16 + l15;
                const float v = acc[i][j][r];
                p1 = fmaf(v, av[col], p1);
                p2 = fmaf(v, av[128 + col], p2);
            }
            #pragma unroll
            for (int o = 1; o < 16; o <<= 1) {
                p1 += __shfl_xor(p1, o);
                p2 += __shfl_xor(p2, o);
            }
            if (l15 == 0) {
                const int rl = wm * 32 + i * 16 + lhi * 4 + r;   // 0..63
                sc[wn * 64 + rl]       = p1;
                sc[128 + wn * 64 + rl] = p2;
            }
        }
    }
    __syncthreads();
    if (tid < 64) {
        const int gr = bm + tid;
        if (gr < Nn) {
            s1[gr] = sc[tid] + sc[64 + tid];
            s2[gr] = sc[128 + tid] + sc[192 + tid];
        }
    }
}

// ---------------- bucketed scatter, fused leaky-relu, single uint4 write ----------------
__global__ __launch_bounds__(256) void scatter_kernel(const int* __restrict__ tio,
                                                      const int* __restrict__ adj,
                                                      const float* __restrict__ s1,
                                                      const float* __restrict__ s2,
                                                      int* __restrict__ cursor,
                                                      uint4* __restrict__ e4, int E) {
    const int k = blockIdx.x * 256 + threadIdx.x;
    if (k >= E) return;
    const int t   = tio[k];
    const int src = adj[k];
    const int dst = adj[E + k];
    float ev = s1[src] + s2[dst];
    ev = ev > 0.f ? ev : 0.2f * ev;          // leaky_relu(0.2)
    const int pos = atomicAdd(&cursor[t], 1);
    if (pos < CAP) {
        e4[(size_t)t * CAP + pos] = make_uint4((unsigned)k, (unsigned)dst,
                                               __float_as_uint(ev), 0u);
    }
}

// ---------------- per-row: dedup + softmax + 4-deep pipelined gather + ELU ----------------
__device__ __forceinline__ void fma8(float* a, float p, uint4 v) {
    a[0] = fmaf(p, bf2f((unsigned short)(v.x)),       a[0]);
    a[1] = fmaf(p, bf2f((unsigned short)(v.x >> 16)), a[1]);
    a[2] = fmaf(p, bf2f((unsigned short)(v.y)),       a[2]);
    a[3] = fmaf(p, bf2f((unsigned short)(v.y >> 16)), a[3]);
    a[4] = fmaf(p, bf2f((unsigned short)(v.z)),       a[4]);
    a[5] = fmaf(p, bf2f((unsigned short)(v.z >> 16)), a[5]);
    a[6] = fmaf(p, bf2f((unsigned short)(v.w)),       a[6]);
    a[7] = fmaf(p, bf2f((unsigned short)(v.w >> 16)), a[7]);
}

__global__ __launch_bounds__(256) void row_kernel(const int* __restrict__ cursor,
                                                  const uint4* __restrict__ e4,
                                                  const unsigned short* __restrict__ Hb,
                                                  float* __restrict__ out, int Nn) {
    __shared__ int   sh_dst[CAP];
    __shared__ int   sh_kk[CAP];
    __shared__ float sh_p[CAP];
    __shared__ unsigned char sh_act[CAP];
    __shared__ float psum[16][128];
    __shared__ float red[4];
    const int row  = blockIdx.x;
    const int tid  = threadIdx.x;
    const int lane = tid & 63;
    const int wave = tid >> 6;
    int cnt = cursor[row];
    if (cnt > CAP) cnt = CAP;
    const size_t base = (size_t)row * CAP;

    for (int i = tid; i < cnt; i += 256) {
        const uint4 v = e4[base + i];
        sh_kk[i]  = (int)v.x;
        sh_dst[i] = (int)v.y;
        sh_p[i]   = __uint_as_float(v.z);
    }
    __syncthreads();

    // dedup (last write wins == max edge index) + row max over active edges
    float lm = -3.0e38f;
    for (int i = tid; i < cnt; i += 256) {
        const int dst = sh_dst[i];
        const int kk  = sh_kk[i];
        bool act = true;
        for (int j = 0; j < cnt; ++j)
            if (sh_dst[j] == dst && sh_kk[j] > kk) { act = false; break; }
        sh_act[i] = act ? 1 : 0;
        if (act) lm = fmaxf(lm, sh_p[i]);
    }
    #pragma unroll
    for (int o = 32; o; o >>= 1) lm = fmaxf(lm, __shfl_xor(lm, o));
    if (lane == 0) red[wave] = lm;
    __syncthreads();
    lm = fmaxf(fmaxf(red[0], red[1]), fmaxf(red[2], red[3]));

    float ls = 0.f;
    for (int i = tid; i < cnt; i += 256) {
        const float p = sh_act[i] ? __expf(sh_p[i] - lm) : 0.f;
        sh_p[i] = p;
        ls += p;
    }
    #pragma unroll
    for (int o = 32; o; o >>= 1) ls += __shfl_xor(ls, o);
    __syncthreads();                       // red[] reuse + sh_p visibility
    if (lane == 0) red[wave] = ls;
    __syncthreads();
    ls = red[0] + red[1] + red[2] + red[3];
    const float inv = (cnt > 0 && ls > 0.f) ? 1.f / ls : 0.f;

    // gather: group (tid>>4) handles edges j, j+16, j+32, j+48 in flight
    const int grp  = tid >> 4;
    const int slot = tid & 15;
    float acc8[8];
    #pragma unroll
    for (int d = 0; d < 8; ++d) acc8[d] = 0.f;

    int j = grp;
    for (; j + 48 < cnt; j += 64) {        // 4 independent gathers in flight
        const int   d0 = sh_dst[j],      d1 = sh_dst[j + 16];
        const int   d2 = sh_dst[j + 32], d3 = sh_dst[j + 48];
        const float p0 = sh_p[j],        p1 = sh_p[j + 16];
        const float p2 = sh_p[j + 32],   p3 = sh_p[j + 48];
        const uint4 v0 = *(const uint4*)(Hb + (size_t)d0 * OUT_DIM + slot * 8);
        const uint4 v1 = *(const uint4*)(Hb + (size_t)d1 * OUT_DIM + slot * 8);
        const uint4 v2 = *(const uint4*)(Hb + (size_t)d2 * OUT_DIM + slot * 8);
        const uint4 v3 = *(const uint4*)(Hb + (size_t)d3 * OUT_DIM + slot * 8);
        fma8(acc8, p0, v0);
        fma8(acc8, p1, v1);
        fma8(acc8, p2, v2);
        fma8(acc8, p3, v3);
    }
    for (; j < cnt; j += 16) {
        const float p0 = sh_p[j];
        const int   d0 = sh_dst[j];
        const uint4 v0 = *(const uint4*)(Hb + (size_t)d0 * OUT_DIM + slot * 8);
        fma8(acc8, p0, v0);
    }
    *(float4*)&psum[grp][slot * 8]     = make_float4(acc8[0], acc8[1], acc8[2], acc8[3]);
    *(float4*)&psum[grp][slot * 8 + 4] = make_float4(acc8[4], acc8[5], acc8[6], acc8[7]);
    __syncthreads();

    if (tid < 128) {
        float v = 0.f;
        #pragma unroll
        for (int k2 = 0; k2 < 16; ++k2) v += psum[k2][tid];
        v *= inv;
        if (cnt == 0) {   // empty row: softmax over all -9e15 -> uniform 1/Nn
            float t = 0.f;
            for (int n = 0; n < Nn; ++n) t += bf2f(Hb[(size_t)n * OUT_DIM + tid]);
            v = t / (float)Nn;
        }
        v = v > 0.f ? v : expm1f(v);       // ELU
        out[(size_t)row * OUT_DIM + tid] = v;
    }
}

extern "C" void kernel_launch(void* const* d_in, const int* in_sizes, int n_in,
                              void* d_out, int out_size, void* d_ws, size_t ws_size,
                              hipStream_t stream) {
    const float* features = (const float*)d_in[0];
    const int*   adj      = (const int*)d_in[1];   // [2, E]
    const int*   tio      = (const int*)d_in[2];   // [E]
    const float* Wm       = (const float*)d_in[3]; // [256,128]
    const float* av       = (const float*)d_in[4]; // [256]
    float* out = (float*)d_out;

    const int N = in_sizes[0] / IN_DIM;
    const int E = in_sizes[2];
    const int T = out_size / OUT_DIM;

    char* ws = (char*)d_ws;
    unsigned short* Hb = (unsigned short*)ws; ws += (size_t)N * OUT_DIM * 2;
    unsigned short* Wt = (unsigned short*)ws; ws += (size_t)IN_DIM * OUT_DIM * 2;
    float* s1 = (float*)ws;                   ws += (size_t)N * 4;
    float* s2 = (float*)ws;                   ws += (size_t)N * 4;
    int* cursor = (int*)ws;                   ws += (size_t)T * 4;
    uint4* e4 = (uint4*)ws;                   ws += (size_t)T * CAP * 16;

    wt_kernel<<<(IN_DIM * OUT_DIM) / 256, 256, 0, stream>>>(Wm, Wt, cursor, T);
    gemm_h<<<(N + 63) / 64, 256, 0, stream>>>(features, Wt, av, Hb, s1, s2, N);
    scatter_kernel<<<(E + 255) / 256, 256, 0, stream>>>(tio, adj, s1, s2, cursor, e4, E);
    row_kernel<<<T, 256, 0, stream>>>(cursor, e4, Hb, out, N);
}